// Round 1
// 85.484 us; speedup vs baseline: 1.0049x; 1.0049x over previous
//
#include <hip/hip_runtime.h>
#include <hip/hip_bf16.h>

// out[t,z] = sum_i f[t,i] * ( sum_j a[t,j] * C[i,j,z] )
// R12 = R11 minus the per-slab barrier machinery. The 16 per-slab
// __syncthreads each forced s_waitcnt vmcnt(0) lgkmcnt(0), draining the
// global B prefetch every slab (m97-ceiling mechanism). LDS B-sharing only
// saved L2 traffic (128 vs 256 MiB) which has >=1.6x headroom, so:
//   - each wave global-loads its own 4 ks-chunks per slab (identical
//     per-lane fragment addressing -> bit-identical MFMA operands),
//   - register double-buffer Bg[2][4], depth-1 prefetch, counted vmcnt,
//   - ZERO barriers in the K-loop (one barrier total for the fpk stage).
// Wave tile 64x16, block 4 waves (2mg x 2zg), grid 1024 = 32mt x 4zp x 8kp,
// kp=bid&7 -> XCD-affine CT chunk (512 KiB/XCD, L2-resident).
// ws: [0,16MB) fp32 partials [kp][4096][128]; [16,20MB) CTf; [20,21MB) APK.

typedef __attribute__((ext_vector_type(8))) short bf16x8;
typedef __attribute__((ext_vector_type(4))) float f32x4;

__device__ __forceinline__ unsigned pkbf16(float x, float y) {
    __hip_bfloat162 h = __float22bfloat162_rn(make_float2(x, y));
    unsigned u; __builtin_memcpy(&u, &h, sizeof(u));
    return u;
}
__device__ __forceinline__ float bf16lo(unsigned u) {
    unsigned v = u << 16; float f; __builtin_memcpy(&f, &v, 4); return f;
}
__device__ __forceinline__ float bf16hi(unsigned u) {
    unsigned v = u & 0xFFFF0000u; float f; __builtin_memcpy(&f, &v, 4); return f;
}

// ---------- prep: transpose C->CTf (bid<512) + pack a->APK (bid>=512) ----------
__global__ __launch_bounds__(256) void cooc_prep(
    const float* __restrict__ Cc, const float* __restrict__ fa,
    ushort* __restrict__ CT, ushort* __restrict__ APK)
{
    const int bid = blockIdx.x;
    const int t = threadIdx.x;
    if (bid < 512) {
        __shared__ float tile[32][132];
        const int i  = bid >> 2;
        const int j0 = (bid & 3) * 32;
        {
            const int jj = t >> 3;
            const int zb = (t & 7) * 16;
            const float* src = Cc + (size_t)i * 16384 + (size_t)(j0 + jj) * 128 + zb;
            #pragma unroll
            for (int k = 0; k < 4; ++k)
                *(float4*)&tile[jj][zb + k * 4] = *(const float4*)(src + k * 4);
        }
        __syncthreads();
        {
            const int z = t >> 1;
            const int h = t & 1;
            unsigned o[8];
            #pragma unroll
            for (int p = 0; p < 8; ++p)
                o[p] = pkbf16(tile[h * 16 + 2 * p][z], tile[h * 16 + 2 * p + 1][z]);
            const int c0 = (j0 >> 3) + h * 2;
            ushort* dst = CT + (size_t)i * 16384 + (size_t)(z >> 4) * 2048
                             + (size_t)c0 * 128 + (z & 15) * 8;
            *(uint4*)dst         = make_uint4(o[0], o[1], o[2], o[3]);
            *(uint4*)(dst + 128) = make_uint4(o[4], o[5], o[6], o[7]);
        }
    } else {
        const int g = bid - 512;           // 0..255: 16-row group
        const int ks = t >> 6, lk = (t >> 4) & 3, lm = t & 15;
        (void)ks; (void)lk; (void)lm;
        const float* src = fa + (size_t)(g * 16 + (t & 15)) * 256 + 128
                              + (t >> 6) * 32 + ((t >> 4) & 3) * 8;
        float4 q0 = *(const float4*)src;
        float4 q1 = *(const float4*)(src + 4);
        *(uint4*)(APK + (size_t)g * 2048 + t * 8) =
            make_uint4(pkbf16(q0.x, q0.y), pkbf16(q0.z, q0.w),
                       pkbf16(q1.x, q1.y), pkbf16(q1.z, q1.w));
    }
}

// ---------- main ----------
template<int USE_WS>
__global__ __launch_bounds__(256, 3) void cooc_main(
    const float* __restrict__ fa, const ushort* __restrict__ CT,
    const ushort* __restrict__ APK, float* __restrict__ dst)
{
    __shared__ ushort fpk[16][128];         // f bf16 [i_local][row] : 4 KB

    const int bid = blockIdx.x;
    const int kp = bid & 7, zp = (bid >> 3) & 3, mtile = bid >> 5;
    const int t0 = mtile * 128, i0 = kp * 16;
    const int tid = threadIdx.x, lane = tid & 63, wv = tid >> 6;
    const int mg = wv >> 1, zg = wv & 1;
    const int lm = lane & 15, lk = lane >> 4;

    // stage f -> LDS as bf16 [i][row]
    {
        const int row = tid & 127;
        const int sh = (tid >> 7) * 8;
        const float* fp = fa + (size_t)(t0 + row) * 256 + i0 + sh;
        float4 v0 = *(const float4*)fp;
        float4 v1 = *(const float4*)(fp + 4);
        fpk[sh + 0][row] = (ushort)(pkbf16(v0.x, v0.x) & 0xFFFF);
        fpk[sh + 1][row] = (ushort)(pkbf16(v0.y, v0.y) & 0xFFFF);
        fpk[sh + 2][row] = (ushort)(pkbf16(v0.z, v0.z) & 0xFFFF);
        fpk[sh + 3][row] = (ushort)(pkbf16(v0.w, v0.w) & 0xFFFF);
        fpk[sh + 4][row] = (ushort)(pkbf16(v1.x, v1.x) & 0xFFFF);
        fpk[sh + 5][row] = (ushort)(pkbf16(v1.y, v1.y) & 0xFFFF);
        fpk[sh + 6][row] = (ushort)(pkbf16(v1.z, v1.z) & 0xFFFF);
        fpk[sh + 7][row] = (ushort)(pkbf16(v1.w, v1.w) & 0xFFFF);
    }

    // A fragments: 16 contiguous 1 KB wave-loads (rows mg*64 .. +63)
    bf16x8 a_pk[4][4];                     // 64 regs
    {
        const ushort* ap = APK + (size_t)((t0 >> 4) + mg * 4) * 2048 + lane * 8;
        #pragma unroll
        for (int m = 0; m < 4; ++m)
            #pragma unroll
            for (int ks = 0; ks < 4; ++ks)
                a_pk[m][ks] = *(const bf16x8*)(ap + (size_t)m * 2048 + ks * 512);
    }

    // B source for this wave's zg slice: 4 ks-chunks of 1 KB per slab
    const ushort* bbase = CT + (size_t)i0 * 16384
                             + (size_t)(zp * 2 + zg) * 2048 + lane * 8;

    // prologue: load slab 0 into parity 0
    bf16x8 Bg[2][4];                       // 32 regs, depth-1 double buffer
    #pragma unroll
    for (int c = 0; c < 4; ++c)
        Bg[0][c] = *(const bf16x8*)(bbase + c * 512);

    __syncthreads();                       // fpk ready (only barrier)

    float acc[4][4];
    #pragma unroll
    for (int m = 0; m < 4; ++m)
        #pragma unroll
        for (int r = 0; r < 4; ++r) acc[m][r] = 0.f;

    #pragma unroll 2
    for (int s = 0; s < 16; ++s) {
        const int cur = s & 1;             // compile-time under unroll 2

        // 1) prefetch slab s+1 into the other parity (stays in flight
        //    across the whole slab-s compute; no barrier ever drains it)
        if (s < 15) {
            const ushort* p = bbase + (size_t)(s + 1) * 16384;
            #pragma unroll
            for (int c = 0; c < 4; ++c)
                Bg[cur ^ 1][c] = *(const bf16x8*)(p + c * 512);
        }

        // 2) f for this slab: 4 x ds_read_b64 (bf16 x4: rows lk*4..+3)
        uint2 fq[4];
        #pragma unroll
        for (int m = 0; m < 4; ++m)
            fq[m] = *(const uint2*)&fpk[s][mg * 64 + m * 16 + lk * 4];

        // 3) ks-outer / m-inner: 4 independent MFMA chains
        f32x4 g[4];
        #pragma unroll
        for (int m = 0; m < 4; ++m) g[m] = (f32x4){0.f, 0.f, 0.f, 0.f};
        #pragma unroll
        for (int ks = 0; ks < 4; ++ks)
            #pragma unroll
            for (int m = 0; m < 4; ++m)
                g[m] = __builtin_amdgcn_mfma_f32_16x16x32_bf16(
                    a_pk[m][ks], Bg[cur][ks], g[m], 0, 0, 0);

        // 4) fold with f (bf16 -> f32 unpack + FMA)
        #pragma unroll
        for (int m = 0; m < 4; ++m) {
            acc[m][0] += bf16lo(fq[m].x) * g[m][0];
            acc[m][1] += bf16hi(fq[m].x) * g[m][1];
            acc[m][2] += bf16lo(fq[m].y) * g[m][2];
            acc[m][3] += bf16hi(fq[m].y) * g[m][3];
        }
    }

    // epilogue: C/D col=lm, row=lk*4+r
    const int col = zp * 32 + zg * 16 + lm;
    #pragma unroll
    for (int m = 0; m < 4; ++m)
        #pragma unroll
        for (int r = 0; r < 4; ++r) {
            const int row = t0 + mg * 64 + m * 16 + lk * 4 + r;
            if (USE_WS)
                dst[(size_t)kp * 524288 + (size_t)row * 128 + col] = acc[m][r];
            else
                atomicAdd(&dst[(size_t)row * 128 + col], acc[m][r]);
        }
}

__global__ __launch_bounds__(256) void cooc_reduce(const float* __restrict__ ws,
                                                   float* __restrict__ out) {
    const size_t idx = ((size_t)blockIdx.x * 256 + threadIdx.x) * 4;
    float4 a = *(const float4*)(ws + idx);
    #pragma unroll
    for (int k = 1; k < 8; ++k) {
        float4 b = *(const float4*)(ws + (size_t)k * 524288 + idx);
        a.x += b.x; a.y += b.y; a.z += b.z; a.w += b.w;
    }
    *(float4*)(out + idx) = a;
}

extern "C" void kernel_launch(void* const* d_in, const int* in_sizes, int n_in,
                              void* d_out, int out_size, void* d_ws, size_t ws_size,
                              hipStream_t stream) {
    const float* fa = (const float*)d_in[0];   // (4096,256): [:,0:128]=f, [:,128:256]=a
    const float* Cc = (const float*)d_in[1];   // (128,128,128)
    float* out = (float*)d_out;                // (4096,128)

    const size_t PART = (size_t)8 * 524288;                  // fp32 partials: 16 MiB
    const size_t CTOF = PART * sizeof(float);                // 16 MiB
    const size_t CTSZ = (size_t)128 * 128 * 128 * 2;         // 4 MiB
    const size_t APOF = CTOF + CTSZ;                         // 20 MiB
    const size_t APSZ = (size_t)4096 * 128 * 2;              // 1 MiB
    const size_t NEED_FULL = APOF + APSZ;
    const size_t NEED_CT   = CTSZ + APSZ;

    if (ws_size >= NEED_FULL) {
        ushort* CT  = (ushort*)((char*)d_ws + CTOF);
        ushort* APK = (ushort*)((char*)d_ws + APOF);
        cooc_prep<<<768, 256, 0, stream>>>(Cc, fa, CT, APK);
        cooc_main<1><<<1024, 256, 0, stream>>>(fa, CT, APK, (float*)d_ws);
        cooc_reduce<<<512, 256, 0, stream>>>((const float*)d_ws, out);
    } else if (ws_size >= NEED_CT) {
        ushort* CT  = (ushort*)d_ws;
        ushort* APK = (ushort*)((char*)d_ws + CTSZ);
        cooc_prep<<<768, 256, 0, stream>>>(Cc, fa, CT, APK);
        (void)hipMemsetAsync(out, 0, (size_t)out_size * sizeof(float), stream);
        cooc_main<0><<<1024, 256, 0, stream>>>(fa, CT, APK, out);
    } else {
        (void)hipMemsetAsync(out, 0, (size_t)out_size * sizeof(float), stream);
        cooc_main<0><<<1024, 256, 0, stream>>>(fa, (const ushort*)d_ws,
                                               (const ushort*)d_ws, out);
    }
}

// Round 2
// 84.625 us; speedup vs baseline: 1.0150x; 1.0101x over previous
//
#include <hip/hip_runtime.h>
#include <hip/hip_bf16.h>

// out[t,z] = sum_i f[t,i] * ( sum_j a[t,j] * C[i,j,z] )
// R13 = R12 with a 2x-wider wave z-tile (64x32) and tail-free residency.
//   - grid 512 = 32mt x 2zh x 8kp, launch_bounds(256,2) -> exactly 2 blk/CU,
//     single round, zero tail (R12: 1024 @ 3/CU = 768 + 256-block tail).
//   - a_pk (64 VGPR, reused all 16 slabs) now amortized over 32 z-cols:
//     CT L2 traffic halves to 128 MiB.
//   - f staged as f32 in LDS (8 KB): fold = broadcast ds_read_b128 + FMA,
//     no bf16 unpack VALU (-16 ops/slab), better precision.
//   - barrier-free slab loop, reg double-buffered B prefetch (depth 1).
// VGPR ~223 (a_pk 64 + Bg 64 + acc 32 + g 32 + fq 16 + addr) < 256 cap.
// ws: [0,16MB) fp32 partials [kp][4096][128]; [16,20MB) CTf; [20,21MB) APK.

typedef __attribute__((ext_vector_type(8))) short bf16x8;
typedef __attribute__((ext_vector_type(4))) float f32x4;

__device__ __forceinline__ unsigned pkbf16(float x, float y) {
    __hip_bfloat162 h = __float22bfloat162_rn(make_float2(x, y));
    unsigned u; __builtin_memcpy(&u, &h, sizeof(u));
    return u;
}

// ---------- prep: transpose C->CTf (bid<512) + pack a->APK (bid>=512) ----------
__global__ __launch_bounds__(256) void cooc_prep(
    const float* __restrict__ Cc, const float* __restrict__ fa,
    ushort* __restrict__ CT, ushort* __restrict__ APK)
{
    const int bid = blockIdx.x;
    const int t = threadIdx.x;
    if (bid < 512) {
        __shared__ float tile[32][132];
        const int i  = bid >> 2;
        const int j0 = (bid & 3) * 32;
        {
            const int jj = t >> 3;
            const int zb = (t & 7) * 16;
            const float* src = Cc + (size_t)i * 16384 + (size_t)(j0 + jj) * 128 + zb;
            #pragma unroll
            for (int k = 0; k < 4; ++k)
                *(float4*)&tile[jj][zb + k * 4] = *(const float4*)(src + k * 4);
        }
        __syncthreads();
        {
            const int z = t >> 1;
            const int h = t & 1;
            unsigned o[8];
            #pragma unroll
            for (int p = 0; p < 8; ++p)
                o[p] = pkbf16(tile[h * 16 + 2 * p][z], tile[h * 16 + 2 * p + 1][z]);
            const int c0 = (j0 >> 3) + h * 2;
            ushort* dst = CT + (size_t)i * 16384 + (size_t)(z >> 4) * 2048
                             + (size_t)c0 * 128 + (z & 15) * 8;
            *(uint4*)dst         = make_uint4(o[0], o[1], o[2], o[3]);
            *(uint4*)(dst + 128) = make_uint4(o[4], o[5], o[6], o[7]);
        }
    } else {
        const int g = bid - 512;           // 0..255: 16-row group
        const float* src = fa + (size_t)(g * 16 + (t & 15)) * 256 + 128
                              + (t >> 6) * 32 + ((t >> 4) & 3) * 8;
        float4 q0 = *(const float4*)src;
        float4 q1 = *(const float4*)(src + 4);
        *(uint4*)(APK + (size_t)g * 2048 + t * 8) =
            make_uint4(pkbf16(q0.x, q0.y), pkbf16(q0.z, q0.w),
                       pkbf16(q1.x, q1.y), pkbf16(q1.z, q1.w));
    }
}

// ---------- main ----------
template<int USE_WS>
__global__ __launch_bounds__(256, 2) void cooc_main(
    const float* __restrict__ fa, const ushort* __restrict__ CT,
    const ushort* __restrict__ APK, float* __restrict__ dst)
{
    __shared__ float fsh[16][128];          // f fp32 [i_local][row] : 8 KB

    const int bid = blockIdx.x;
    const int kp = bid & 7, zh = (bid >> 3) & 1, mtile = bid >> 4;
    const int t0 = mtile * 128, i0 = kp * 16;
    const int tid = threadIdx.x, lane = tid & 63, wv = tid >> 6;
    const int mg = wv >> 1, zg = wv & 1;
    const int lm = lane & 15, lk = lane >> 4;

    // stage f -> LDS (fp32, conflict-free: lane index = row)
    {
        const int row = tid & 127;
        const int sh = (tid >> 7) * 8;
        const float* fp = fa + (size_t)(t0 + row) * 256 + i0 + sh;
        float4 v0 = *(const float4*)fp;
        float4 v1 = *(const float4*)(fp + 4);
        fsh[sh + 0][row] = v0.x; fsh[sh + 1][row] = v0.y;
        fsh[sh + 2][row] = v0.z; fsh[sh + 3][row] = v0.w;
        fsh[sh + 4][row] = v1.x; fsh[sh + 5][row] = v1.y;
        fsh[sh + 6][row] = v1.z; fsh[sh + 7][row] = v1.w;
    }

    // A fragments: rows mg*64 .. +63, all 4 ks-chunks (reused by all slabs)
    bf16x8 a_pk[4][4];                     // 64 regs
    {
        const ushort* ap = APK + (size_t)((t0 >> 4) + mg * 4) * 2048 + lane * 8;
        #pragma unroll
        for (int m = 0; m < 4; ++m)
            #pragma unroll
            for (int ks = 0; ks < 4; ++ks)
                a_pk[m][ks] = *(const bf16x8*)(ap + (size_t)m * 2048 + ks * 512);
    }

    // B source: this wave covers 32 z (2 zf blocks of 16), 4 ks-chunks each
    const ushort* bbase = CT + (size_t)i0 * 16384
                             + (size_t)(zh * 4 + zg * 2) * 2048 + lane * 8;

    // prologue: slab 0 into parity 0
    bf16x8 Bg[2][2][4];                    // [parity][zf][ks] : 64 regs
    #pragma unroll
    for (int zf = 0; zf < 2; ++zf)
        #pragma unroll
        for (int c = 0; c < 4; ++c)
            Bg[0][zf][c] = *(const bf16x8*)(bbase + zf * 2048 + c * 512);

    __syncthreads();                       // fsh ready (only barrier)

    float acc[4][2][4];
    #pragma unroll
    for (int m = 0; m < 4; ++m)
        #pragma unroll
        for (int zf = 0; zf < 2; ++zf)
            #pragma unroll
            for (int r = 0; r < 4; ++r) acc[m][zf][r] = 0.f;

    #pragma unroll 2
    for (int s = 0; s < 16; ++s) {
        const int cur = s & 1;             // compile-time under unroll 2

        // 1) prefetch slab s+1 into other parity (no barrier ever drains it)
        if (s < 15) {
            const ushort* p = bbase + (size_t)(s + 1) * 16384;
            #pragma unroll
            for (int zf = 0; zf < 2; ++zf)
                #pragma unroll
                for (int c = 0; c < 4; ++c)
                    Bg[cur ^ 1][zf][c] = *(const bf16x8*)(p + zf * 2048 + c * 512);
        }

        // 2) f for this slab: broadcast ds_read_b128 (4 f32 rows) per m
        float4 fq[4];
        #pragma unroll
        for (int m = 0; m < 4; ++m)
            fq[m] = *(const float4*)&fsh[s][mg * 64 + m * 16 + lk * 4];

        // 3) 8 independent MFMA chains (4m x 2zf), ks-outer
        f32x4 g[4][2];
        #pragma unroll
        for (int m = 0; m < 4; ++m)
            #pragma unroll
            for (int zf = 0; zf < 2; ++zf) g[m][zf] = (f32x4){0.f, 0.f, 0.f, 0.f};
        #pragma unroll
        for (int ks = 0; ks < 4; ++ks)
            #pragma unroll
            for (int m = 0; m < 4; ++m)
                #pragma unroll
                for (int zf = 0; zf < 2; ++zf)
                    g[m][zf] = __builtin_amdgcn_mfma_f32_16x16x32_bf16(
                        a_pk[m][ks], Bg[cur][zf][ks], g[m][zf], 0, 0, 0);

        // 4) fold with f (pure f32 FMA, rows lk*4..+3 = .x..w)
        #pragma unroll
        for (int m = 0; m < 4; ++m)
            #pragma unroll
            for (int zf = 0; zf < 2; ++zf) {
                acc[m][zf][0] += fq[m].x * g[m][zf][0];
                acc[m][zf][1] += fq[m].y * g[m][zf][1];
                acc[m][zf][2] += fq[m].z * g[m][zf][2];
                acc[m][zf][3] += fq[m].w * g[m][zf][3];
            }
    }

    // epilogue: C/D col=lm, row=lk*4+r
    const int colbase = (zh * 4 + zg * 2) * 16 + lm;
    #pragma unroll
    for (int m = 0; m < 4; ++m)
        #pragma unroll
        for (int zf = 0; zf < 2; ++zf)
            #pragma unroll
            for (int r = 0; r < 4; ++r) {
                const int row = t0 + mg * 64 + m * 16 + lk * 4 + r;
                const int col = colbase + zf * 16;
                if (USE_WS)
                    dst[(size_t)kp * 524288 + (size_t)row * 128 + col] = acc[m][zf][r];
                else
                    atomicAdd(&dst[(size_t)row * 128 + col], acc[m][zf][r]);
            }
}

__global__ __launch_bounds__(256) void cooc_reduce(const float* __restrict__ ws,
                                                   float* __restrict__ out) {
    const size_t idx = ((size_t)blockIdx.x * 256 + threadIdx.x) * 4;
    float4 a = *(const float4*)(ws + idx);
    #pragma unroll
    for (int k = 1; k < 8; ++k) {
        float4 b = *(const float4*)(ws + (size_t)k * 524288 + idx);
        a.x += b.x; a.y += b.y; a.z += b.z; a.w += b.w;
    }
    *(float4*)(out + idx) = a;
}

extern "C" void kernel_launch(void* const* d_in, const int* in_sizes, int n_in,
                              void* d_out, int out_size, void* d_ws, size_t ws_size,
                              hipStream_t stream) {
    const float* fa = (const float*)d_in[0];   // (4096,256): [:,0:128]=f, [:,128:256]=a
    const float* Cc = (const float*)d_in[1];   // (128,128,128)
    float* out = (float*)d_out;                // (4096,128)

    const size_t PART = (size_t)8 * 524288;                  // fp32 partials: 16 MiB
    const size_t CTOF = PART * sizeof(float);                // 16 MiB
    const size_t CTSZ = (size_t)128 * 128 * 128 * 2;         // 4 MiB
    const size_t APOF = CTOF + CTSZ;                         // 20 MiB
    const size_t APSZ = (size_t)4096 * 128 * 2;              // 1 MiB
    const size_t NEED_FULL = APOF + APSZ;
    const size_t NEED_CT   = CTSZ + APSZ;

    if (ws_size >= NEED_FULL) {
        ushort* CT  = (ushort*)((char*)d_ws + CTOF);
        ushort* APK = (ushort*)((char*)d_ws + APOF);
        cooc_prep<<<768, 256, 0, stream>>>(Cc, fa, CT, APK);
        cooc_main<1><<<512, 256, 0, stream>>>(fa, CT, APK, (float*)d_ws);
        cooc_reduce<<<512, 256, 0, stream>>>((const float*)d_ws, out);
    } else if (ws_size >= NEED_CT) {
        ushort* CT  = (ushort*)d_ws;
        ushort* APK = (ushort*)((char*)d_ws + CTSZ);
        cooc_prep<<<768, 256, 0, stream>>>(Cc, fa, CT, APK);
        (void)hipMemsetAsync(out, 0, (size_t)out_size * sizeof(float), stream);
        cooc_main<0><<<512, 256, 0, stream>>>(fa, CT, APK, out);
    } else {
        (void)hipMemsetAsync(out, 0, (size_t)out_size * sizeof(float), stream);
        cooc_main<0><<<512, 256, 0, stream>>>(fa, (const ushort*)d_ws,
                                              (const ushort*)d_ws, out);
    }
}